// Round 1
// baseline (129.581 us; speedup 1.0000x reference)
//
#include <hip/hip_runtime.h>
#include <math.h>

#define N_ELEMS 200000
#define D 512
#define NCLS 2
#define NINS 8
#define NBLK 256
#define NTHR 256

// "better" for descending top-k with jax tie-break (smaller index wins ties)
__device__ __forceinline__ bool better(float av, int ai, float bv, int bi) {
    return (av > bv) || (av == bv && ai < bi);
}

// Insert (v,i) into sorted-best-first 8-list held in registers (static indexing only).
__device__ __forceinline__ void insert8(float (&lv)[8], int (&li)[8], float v, int i) {
    if (!better(v, i, lv[7], li[7])) return;
    lv[7] = v; li[7] = i;
#pragma unroll
    for (int k = 7; k > 0; --k) {
        if (better(lv[k], li[k], lv[k - 1], li[k - 1])) {
            float tv = lv[k]; lv[k] = lv[k - 1]; lv[k - 1] = tv;
            int ti = li[k]; li[k] = li[k - 1]; li[k - 1] = ti;
        }
    }
}

// LDS tree-merge: each thread's sorted 8-list (2 lists: top & bottom) -> final lists at slot 0.
__device__ __forceinline__ void reduce_lists(float (*sv)[NTHR][8], int (*si)[NTHR][8], int tid) {
    for (int stride = NTHR / 2; stride > 0; stride >>= 1) {
        if (tid < stride) {
#pragma unroll
            for (int l = 0; l < 2; ++l) {
                float av[8]; int ai[8];
#pragma unroll
                for (int k = 0; k < 8; ++k) { av[k] = sv[l][tid][k]; ai[k] = si[l][tid][k]; }
#pragma unroll
                for (int k = 0; k < 8; ++k) {
                    insert8(av, ai, sv[l][tid + stride][k], si[l][tid + stride][k]);
                }
#pragma unroll
                for (int k = 0; k < 8; ++k) { sv[l][tid][k] = av[k]; si[l][tid][k] = ai[k]; }
            }
        }
        __syncthreads();
    }
}

__global__ __launch_bounds__(NTHR) void topk_partial(const int* __restrict__ bl_ptr,
                                                     const float* __restrict__ A,
                                                     float* __restrict__ wsTopV, int* __restrict__ wsTopI,
                                                     float* __restrict__ wsBotV, int* __restrict__ wsBotI) {
    const int bl  = bl_ptr[0];
    const int tid = threadIdx.x;
    const int blk = blockIdx.x;
    const int chunk = (N_ELEMS + NBLK - 1) / NBLK;
    const int start = blk * chunk;
    const int end   = min(N_ELEMS, start + chunk);

    float tv[8]; int ti[8];   // top-8 of A_I
    float bv[8]; int bi[8];   // top-8 of -A_I  (== bottom-8 of A_I, jax tie-break preserved)
#pragma unroll
    for (int k = 0; k < 8; ++k) {
        tv[k] = -INFINITY; ti[k] = 0x7FFFFFFF;
        bv[k] = -INFINITY; bi[k] = 0x7FFFFFFF;
    }

    for (int i = start + tid; i < end; i += NTHR) {
        float v = A[i * NCLS + bl];
        insert8(tv, ti, v, i);
        insert8(bv, bi, -v, i);
    }

    __shared__ float sv[2][NTHR][8];
    __shared__ int   si[2][NTHR][8];
#pragma unroll
    for (int k = 0; k < 8; ++k) {
        sv[0][tid][k] = tv[k]; si[0][tid][k] = ti[k];
        sv[1][tid][k] = bv[k]; si[1][tid][k] = bi[k];
    }
    __syncthreads();
    reduce_lists(sv, si, tid);

    if (tid < 8) {
        wsTopV[blk * 8 + tid] = sv[0][0][tid]; wsTopI[blk * 8 + tid] = si[0][0][tid];
        wsBotV[blk * 8 + tid] = sv[1][0][tid]; wsBotI[blk * 8 + tid] = si[1][0][tid];
    }
}

__global__ __launch_bounds__(NTHR) void topk_final(const float* __restrict__ h,
                                                   const float* __restrict__ W,
                                                   const float* __restrict__ bvec,
                                                   const float* __restrict__ wsTopV, const int* __restrict__ wsTopI,
                                                   const float* __restrict__ wsBotV, const int* __restrict__ wsBotI,
                                                   float* __restrict__ out) {
    const int tid = threadIdx.x;

    // Thread t's initial list = block t's (already sorted) candidate list.
    float tv[8]; int ti[8]; float bv[8]; int bi[8];
#pragma unroll
    for (int k = 0; k < 8; ++k) {
        tv[k] = wsTopV[tid * 8 + k]; ti[k] = wsTopI[tid * 8 + k];
        bv[k] = wsBotV[tid * 8 + k]; bi[k] = wsBotI[tid * 8 + k];
    }

    __shared__ float sv[2][NTHR][8];
    __shared__ int   si[2][NTHR][8];
#pragma unroll
    for (int k = 0; k < 8; ++k) {
        sv[0][tid][k] = tv[k]; si[0][tid][k] = ti[k];
        sv[1][tid][k] = bv[k]; si[1][tid][k] = bi[k];
    }
    __syncthreads();
    reduce_lists(sv, si, tid);

    __shared__ int fidx[16];
    if (tid < 16) fidx[tid] = (tid < 8) ? si[0][0][tid] : si[1][0][tid - 8];
    __syncthreads();

    // 16 groups of 16 lanes; group g computes row g's two dot products over D=512.
    const int g = tid >> 4;
    const int t = tid & 15;
    const float* hrow = h + (long long)fidx[g] * D;
    float s0 = 0.f, s1 = 0.f;
    for (int d = t; d < D; d += 16) {
        float x = hrow[d];
        s0 += x * W[d * NCLS + 0];
        s1 += x * W[d * NCLS + 1];
    }
#pragma unroll
    for (int m = 8; m >= 1; m >>= 1) {
        s0 += __shfl_xor(s0, m, 16);
        s1 += __shfl_xor(s1, m, 16);
    }
    if (t == 0) {
        float l0 = s0 + bvec[0];
        float l1 = s1 + bvec[1];
        float mx = fmaxf(l0, l1);
        float e0 = expf(l0 - mx), e1 = expf(l1 - mx);
        float inv = 1.0f / (e0 + e1);
        out[16 + g * 2 + 0] = l0;            // logits_unnorm
        out[16 + g * 2 + 1] = l1;
        out[48 + g * 2 + 0] = e0 * inv;      // logits (softmax)
        out[48 + g * 2 + 1] = e1 * inv;
    }
    if (tid < 16) out[tid] = (tid < 8) ? 1.0f : 0.0f;  // ins_labels
}

extern "C" void kernel_launch(void* const* d_in, const int* in_sizes, int n_in,
                              void* d_out, int out_size, void* d_ws, size_t ws_size,
                              hipStream_t stream) {
    const int*   bl = (const int*)  d_in[0];
    const float* h  = (const float*)d_in[1];
    const float* A  = (const float*)d_in[2];
    const float* W  = (const float*)d_in[3];
    const float* b  = (const float*)d_in[4];
    float* out = (float*)d_out;

    // workspace layout: 4 arrays of NBLK*8 = 2048 entries each (32 KB total)
    char* ws = (char*)d_ws;
    float* wsTopV = (float*)(ws + 0);
    int*   wsTopI = (int*)  (ws + 2048 * 4);
    float* wsBotV = (float*)(ws + 2048 * 8);
    int*   wsBotI = (int*)  (ws + 2048 * 12);

    topk_partial<<<NBLK, NTHR, 0, stream>>>(bl, A, wsTopV, wsTopI, wsBotV, wsBotI);
    topk_final<<<1, NTHR, 0, stream>>>(h, W, b, wsTopV, wsTopI, wsBotV, wsBotI, out);
}

// Round 2
// 46.777 us; speedup vs baseline: 2.7702x; 2.7702x over previous
//
#include <hip/hip_runtime.h>
#include <math.h>

#define N_ELEMS 200000
#define D 512
#define NCLS 2
#define NINS 8
#define NBLK 256
#define NTHR 256

typedef unsigned long long u64;
typedef unsigned int u32;

// Order-preserving float->uint map: a > b  <=>  mono(a) > mono(b)
__device__ __forceinline__ u32 mono(float f) {
    u32 u = __float_as_uint(f);
    return u ^ (u32)(((int)u >> 31) | 0x80000000);
}

// key packs (value, index): larger value wins; on equal value, SMALLER index wins
// (jax top_k tie-break) because we store ~i in the low 32 bits.
__device__ __forceinline__ u64 make_key(float v, int i) {
    return ((u64)mono(v) << 32) | (u32)(~(u32)i);
}
__device__ __forceinline__ int key_idx(u64 k) { return (int)(~(u32)k); }

__device__ __forceinline__ u64 shfl_xor_u64(u64 x, int m) {
    u32 lo = (u32)x, hi = (u32)(x >> 32);
    lo = __shfl_xor(lo, m, 64);
    hi = __shfl_xor(hi, m, 64);
    return ((u64)hi << 32) | lo;
}

__device__ __forceinline__ u64 wave_max_u64(u64 k) {
#pragma unroll
    for (int m = 1; m < 64; m <<= 1) {
        u64 o = shfl_xor_u64(k, m);
        if (o > k) k = o;
    }
    return k;
}

// Block-wide max over 256 threads (4 waves). Two __syncthreads per call.
__device__ __forceinline__ u64 block_max_u64(u64 k, u64* wmax, u64* winslot, int tid) {
    k = wave_max_u64(k);
    if ((tid & 63) == 0) wmax[tid >> 6] = k;
    __syncthreads();
    if (tid == 0) {
        u64 w = wmax[0];
        if (wmax[1] > w) w = wmax[1];
        if (wmax[2] > w) w = wmax[2];
        if (wmax[3] > w) w = wmax[3];
        *winslot = w;
    }
    __syncthreads();
    return *winslot;
}

__global__ __launch_bounds__(NTHR) void ins_fused(const int* __restrict__ bl_ptr,
                                                  const float* __restrict__ A,
                                                  const float* __restrict__ h,
                                                  const float* __restrict__ W,
                                                  const float* __restrict__ bvec,
                                                  u64* __restrict__ wsTop,
                                                  u64* __restrict__ wsBot,
                                                  u32* __restrict__ counter,
                                                  float* __restrict__ out) {
    const int tid = threadIdx.x;
    const int blk = blockIdx.x;
    const int bl  = bl_ptr[0];

    __shared__ u64 wmax[4];
    __shared__ u64 winslot;

    // ---- Phase 1: per-block top-8 / bottom-8 over this block's chunk of A ----
    const int chunk = (N_ELEMS + NBLK - 1) / NBLK;   // 782
    const int start = blk * chunk;
    const int end   = min(N_ELEMS, start + chunk);

    const float2* A2 = (const float2*)A;   // A is (N,1,2) contiguous -> float2 per row

    u64 ct[4], cb[4];
#pragma unroll
    for (int it = 0; it < 4; ++it) {
        int i = start + tid + it * NTHR;
        if (i < end) {
            float2 a2 = A2[i];
            float v = (bl == 0) ? a2.x : a2.y;
            ct[it] = make_key(v, i);
            cb[it] = make_key(-v, i);
        } else {
            ct[it] = 0ULL;
            cb[it] = 0ULL;
        }
    }

    for (int r = 0; r < NINS; ++r) {
        u64 local = ct[0];
#pragma unroll
        for (int it = 1; it < 4; ++it) if (ct[it] > local) local = ct[it];
        u64 win = block_max_u64(local, wmax, &winslot, tid);
        if (tid == 0) wsTop[blk * NINS + r] = win;   // descending order
#pragma unroll
        for (int it = 0; it < 4; ++it) if (ct[it] == win) ct[it] = 0ULL;
    }
    for (int r = 0; r < NINS; ++r) {
        u64 local = cb[0];
#pragma unroll
        for (int it = 1; it < 4; ++it) if (cb[it] > local) local = cb[it];
        u64 win = block_max_u64(local, wmax, &winslot, tid);
        if (tid == 0) wsBot[blk * NINS + r] = win;
#pragma unroll
        for (int it = 0; it < 4; ++it) if (cb[it] == win) cb[it] = 0ULL;
    }

    // ---- Completion count: last block finalizes ----
    __threadfence();                       // make ws writes visible device-wide
    __shared__ u32 doneLds;
    if (tid == 0) doneLds = atomicAdd(counter, 1u);
    __syncthreads();
    if (doneLds != NBLK - 1) return;
    __threadfence();                       // acquire: see all blocks' ws writes

    // ---- Phase 2 (last block only): merge 256 sorted 8-runs -> global 8 ----
    __shared__ u64 keys[NBLK * NINS];      // 16 KB
    __shared__ int fidx[2 * NINS];

#pragma unroll
    for (int k = 0; k < NINS; ++k) keys[tid * NINS + k] = wsTop[tid * NINS + k];
    __syncthreads();
    {
        int p = 0;
        for (int r = 0; r < NINS; ++r) {
            u64 cur = (p < NINS) ? keys[tid * NINS + p] : 0ULL;
            u64 win = block_max_u64(cur, wmax, &winslot, tid);
            if (cur == win && cur != 0ULL) p++;
            if (tid == 0) fidx[r] = key_idx(win);
        }
    }
    __syncthreads();
#pragma unroll
    for (int k = 0; k < NINS; ++k) keys[tid * NINS + k] = wsBot[tid * NINS + k];
    __syncthreads();
    {
        int p = 0;
        for (int r = 0; r < NINS; ++r) {
            u64 cur = (p < NINS) ? keys[tid * NINS + p] : 0ULL;
            u64 win = block_max_u64(cur, wmax, &winslot, tid);
            if (cur == win && cur != 0ULL) p++;
            if (tid == 0) fidx[NINS + r] = key_idx(win);
        }
    }
    __syncthreads();

    // ---- Phase 3: logits for the 16 selected rows; 16 groups x 16 lanes ----
    const int g = tid >> 4;
    const int t = tid & 15;
    const long long row = fidx[g];
    const float4* h4 = (const float4*)(h + row * (long long)D);
    const float2* W2 = (const float2*)W;

    float s0 = 0.f, s1 = 0.f;
#pragma unroll
    for (int it = 0; it < 8; ++it) {
        int d4 = t + it * 16;              // float4 index; covers d = 4*d4 .. 4*d4+3
        float4 x = h4[d4];
        float2 w0 = W2[d4 * 4 + 0];
        float2 w1 = W2[d4 * 4 + 1];
        float2 w2 = W2[d4 * 4 + 2];
        float2 w3 = W2[d4 * 4 + 3];
        s0 += x.x * w0.x + x.y * w1.x + x.z * w2.x + x.w * w3.x;
        s1 += x.x * w0.y + x.y * w1.y + x.z * w2.y + x.w * w3.y;
    }
#pragma unroll
    for (int m = 8; m >= 1; m >>= 1) {
        s0 += __shfl_xor(s0, m, 16);
        s1 += __shfl_xor(s1, m, 16);
    }
    if (t == 0) {
        float l0 = s0 + bvec[0];
        float l1 = s1 + bvec[1];
        float mx = fmaxf(l0, l1);
        float e0 = expf(l0 - mx), e1 = expf(l1 - mx);
        float inv = 1.0f / (e0 + e1);
        out[16 + g * 2 + 0] = l0;          // logits_unnorm
        out[16 + g * 2 + 1] = l1;
        out[48 + g * 2 + 0] = e0 * inv;    // softmax
        out[48 + g * 2 + 1] = e1 * inv;
    }
    if (tid < 16) out[tid] = (tid < 8) ? 1.0f : 0.0f;  // ins_labels
}

extern "C" void kernel_launch(void* const* d_in, const int* in_sizes, int n_in,
                              void* d_out, int out_size, void* d_ws, size_t ws_size,
                              hipStream_t stream) {
    const int*   bl = (const int*)  d_in[0];
    const float* h  = (const float*)d_in[1];
    const float* A  = (const float*)d_in[2];
    const float* W  = (const float*)d_in[3];
    const float* b  = (const float*)d_in[4];
    float* out = (float*)d_out;

    // ws layout: wsTop u64[2048] @0 (16KB) | wsBot u64[2048] @16KB | counter u32 @32KB
    char* ws = (char*)d_ws;
    u64* wsTop   = (u64*)(ws + 0);
    u64* wsBot   = (u64*)(ws + 16384);
    u32* counter = (u32*)(ws + 32768);

    hipMemsetAsync(counter, 0, sizeof(u32), stream);   // ws is poisoned 0xAA; reset each call
    ins_fused<<<NBLK, NTHR, 0, stream>>>(bl, A, h, W, b, wsTop, wsBot, counter, out);
}

// Round 3
// 43.120 us; speedup vs baseline: 3.0051x; 1.0848x over previous
//
#include <hip/hip_runtime.h>
#include <math.h>

#define N_ELEMS 200000
#define D 512
#define NCLS 2
#define NINS 8
#define NBLK 256
#define NTHR 256

typedef unsigned long long u64;
typedef unsigned int u32;

// Order-preserving float->uint map: a > b  <=>  mono(a) > mono(b)
__device__ __forceinline__ u32 mono(float f) {
    u32 u = __float_as_uint(f);
    return u ^ (u32)(((int)u >> 31) | 0x80000000);
}

// key packs (value, index): larger value wins; equal value -> SMALLER index wins
// (jax top_k tie-break) because low 32 bits hold ~i.
__device__ __forceinline__ u64 make_key(float v, int i) {
    return ((u64)mono(v) << 32) | (u32)(~(u32)i);
}
__device__ __forceinline__ int key_idx(u64 k) { return (int)(~(u32)k); }

__device__ __forceinline__ u64 shfl_xor_u64(u64 x, int m) {
    u32 lo = (u32)x, hi = (u32)(x >> 32);
    lo = __shfl_xor(lo, m, 64);
    hi = __shfl_xor(hi, m, 64);
    return ((u64)hi << 32) | lo;
}

// max across all 64 lanes (inactive-source lanes must hold 0)
__device__ __forceinline__ u64 wave_max_u64(u64 k) {
#pragma unroll
    for (int m = 1; m < 64; m <<= 1) {
        u64 o = shfl_xor_u64(k, m);
        if (o > k) k = o;
    }
    return k;
}

__global__ __launch_bounds__(NTHR) void ins_fused(const int* __restrict__ bl_ptr,
                                                  const float* __restrict__ A,
                                                  const float* __restrict__ h,
                                                  const float* __restrict__ W,
                                                  const float* __restrict__ bvec,
                                                  u64* __restrict__ wsTop,
                                                  u64* __restrict__ wsBot,
                                                  u32* __restrict__ counter,
                                                  float* __restrict__ out) {
    const int tid  = threadIdx.x;
    const int blk  = blockIdx.x;
    const int wid  = tid >> 6;    // wave 0..3
    const int lane = tid & 63;
    const int bl   = bl_ptr[0];

    __shared__ u64 cand[2][4][8];   // [list][wave][rank], per-wave top-8s
    __shared__ u64 cand2[4][8];     // phase-2 per-wave results
    __shared__ int fidx[16];
    __shared__ u32 doneLds;

    // ---- Phase 1: per-block top-8 / bottom-8, shuffle-only + 1 barrier ----
    const int chunk = (N_ELEMS + NBLK - 1) / NBLK;   // 782
    const int start = blk * chunk;
    const int end   = min(N_ELEMS, start + chunk);
    const float2* A2 = (const float2*)A;             // A is (N,1,2) -> float2/row

    u64 t0, t1, t2, t3, b0, b1, b2, b3;
    {
        int i0 = start + tid, i1 = i0 + NTHR, i2 = i1 + NTHR, i3 = i2 + NTHR;
        float2 a;
        if (i0 < end) { a = A2[i0]; float v = bl ? a.y : a.x; t0 = make_key(v, i0); b0 = make_key(-v, i0); } else { t0 = b0 = 0; }
        if (i1 < end) { a = A2[i1]; float v = bl ? a.y : a.x; t1 = make_key(v, i1); b1 = make_key(-v, i1); } else { t1 = b1 = 0; }
        if (i2 < end) { a = A2[i2]; float v = bl ? a.y : a.x; t2 = make_key(v, i2); b2 = make_key(-v, i2); } else { t2 = b2 = 0; }
        if (i3 < end) { a = A2[i3]; float v = bl ? a.y : a.x; t3 = make_key(v, i3); b3 = make_key(-v, i3); } else { t3 = b3 = 0; }
    }

#pragma unroll
    for (int r = 0; r < NINS; ++r) {            // top list: 8 rounds, no barriers
        u64 m01 = t0 > t1 ? t0 : t1;
        u64 m23 = t2 > t3 ? t2 : t3;
        u64 lm  = m01 > m23 ? m01 : m23;
        u64 w   = wave_max_u64(lm);
        if (lane == 0) cand[0][wid][r] = w;
        if (t0 == w) t0 = 0; if (t1 == w) t1 = 0; if (t2 == w) t2 = 0; if (t3 == w) t3 = 0;
    }
#pragma unroll
    for (int r = 0; r < NINS; ++r) {            // bottom list
        u64 m01 = b0 > b1 ? b0 : b1;
        u64 m23 = b2 > b3 ? b2 : b3;
        u64 lm  = m01 > m23 ? m01 : m23;
        u64 w   = wave_max_u64(lm);
        if (lane == 0) cand[1][wid][r] = w;
        if (b0 == w) b0 = 0; if (b1 == w) b1 = 0; if (b2 == w) b2 = 0; if (b3 == w) b3 = 0;
    }
    __syncthreads();

    if (wid < 2) {   // wave 0 merges top (32 cands), wave 1 merges bottom — in parallel
        u64 k = (lane < 32) ? cand[wid][lane >> 3][lane & 7] : 0ULL;
        u64* dst = (wid == 0) ? (wsTop + blk * NINS) : (wsBot + blk * NINS);
#pragma unroll
        for (int r = 0; r < NINS; ++r) {
            u64 w = wave_max_u64(k);
            if (lane == 0) dst[r] = w;          // sorted descending
            if (k == w) k = 0;
        }
    }

    // ---- arrive; last block finalizes ----
    __threadfence();
    if (tid == 0) doneLds = atomicAdd(counter, 1u);
    __syncthreads();
    if (doneLds != NBLK - 1) return;
    __threadfence();

    // ---- Phase 2: merge 2048 keys per list; waves 0-1 top, waves 2-3 bottom ----
    {
        const u64* src = (wid < 2) ? wsTop : wsBot;
        u64 k[16];
#pragma unroll
        for (int j = 0; j < 16; ++j) k[j] = src[(wid & 1) * 1024 + lane * 16 + j];
#pragma unroll
        for (int r = 0; r < NINS; ++r) {
            u64 a01 = k[0]  > k[1]  ? k[0]  : k[1];
            u64 a23 = k[2]  > k[3]  ? k[2]  : k[3];
            u64 a45 = k[4]  > k[5]  ? k[4]  : k[5];
            u64 a67 = k[6]  > k[7]  ? k[6]  : k[7];
            u64 a89 = k[8]  > k[9]  ? k[8]  : k[9];
            u64 aab = k[10] > k[11] ? k[10] : k[11];
            u64 acd = k[12] > k[13] ? k[12] : k[13];
            u64 aef = k[14] > k[15] ? k[14] : k[15];
            u64 b0_ = a01 > a23 ? a01 : a23;
            u64 b1_ = a45 > a67 ? a45 : a67;
            u64 b2_ = a89 > aab ? a89 : aab;
            u64 b3_ = acd > aef ? acd : aef;
            u64 c0_ = b0_ > b1_ ? b0_ : b1_;
            u64 c1_ = b2_ > b3_ ? b2_ : b3_;
            u64 lm  = c0_ > c1_ ? c0_ : c1_;
            u64 w   = wave_max_u64(lm);
            if (lane == 0) cand2[wid][r] = w;
#pragma unroll
            for (int j = 0; j < 16; ++j) if (k[j] == w) k[j] = 0;
        }
    }
    __syncthreads();
    if ((wid & 1) == 0) {   // wave 0: top cand2[0..1]; wave 2: bottom cand2[2..3]
        u64 k = (lane < 16) ? cand2[wid + (lane >> 3)][lane & 7] : 0ULL;
#pragma unroll
        for (int r = 0; r < NINS; ++r) {
            u64 w = wave_max_u64(k);
            if (lane == 0) fidx[(wid >> 1) * NINS + r] = key_idx(w);
            if (k == w) k = 0;
        }
    }
    __syncthreads();

    // ---- Phase 3: 16 groups x 16 lanes compute the two logits per row ----
    const int g = tid >> 4;
    const int t = tid & 15;
    const long long row = fidx[g];
    const float4* h4 = (const float4*)(h + row * (long long)D);
    const float2* W2 = (const float2*)W;

    float s0 = 0.f, s1 = 0.f;
#pragma unroll
    for (int it = 0; it < 8; ++it) {
        int d4 = t + it * 16;
        float4 x = h4[d4];
        float2 w0 = W2[d4 * 4 + 0];
        float2 w1 = W2[d4 * 4 + 1];
        float2 w2 = W2[d4 * 4 + 2];
        float2 w3 = W2[d4 * 4 + 3];
        s0 += x.x * w0.x + x.y * w1.x + x.z * w2.x + x.w * w3.x;
        s1 += x.x * w0.y + x.y * w1.y + x.z * w2.y + x.w * w3.y;
    }
#pragma unroll
    for (int m = 8; m >= 1; m >>= 1) {
        s0 += __shfl_xor(s0, m, 16);
        s1 += __shfl_xor(s1, m, 16);
    }
    if (t == 0) {
        float l0 = s0 + bvec[0];
        float l1 = s1 + bvec[1];
        float mx = fmaxf(l0, l1);
        float e0 = expf(l0 - mx), e1 = expf(l1 - mx);
        float inv = 1.0f / (e0 + e1);
        out[16 + g * 2 + 0] = l0;          // logits_unnorm
        out[16 + g * 2 + 1] = l1;
        out[48 + g * 2 + 0] = e0 * inv;    // softmax
        out[48 + g * 2 + 1] = e1 * inv;
    }
    if (tid < 16) out[tid] = (tid < 8) ? 1.0f : 0.0f;  // ins_labels
}

extern "C" void kernel_launch(void* const* d_in, const int* in_sizes, int n_in,
                              void* d_out, int out_size, void* d_ws, size_t ws_size,
                              hipStream_t stream) {
    const int*   bl = (const int*)  d_in[0];
    const float* h  = (const float*)d_in[1];
    const float* A  = (const float*)d_in[2];
    const float* W  = (const float*)d_in[3];
    const float* b  = (const float*)d_in[4];
    float* out = (float*)d_out;

    // ws layout: wsTop u64[2048] @0 (16KB) | wsBot u64[2048] @16KB | counter u32 @32KB
    char* ws = (char*)d_ws;
    u64* wsTop   = (u64*)(ws + 0);
    u64* wsBot   = (u64*)(ws + 16384);
    u32* counter = (u32*)(ws + 32768);

    hipMemsetAsync(counter, 0, sizeof(u32), stream);   // ws poisoned 0xAA; reset each call
    ins_fused<<<NBLK, NTHR, 0, stream>>>(bl, A, h, W, b, wsTop, wsBot, counter, out);
}